// Round 14
// baseline (290.508 us; speedup 1.0000x reference)
//
#include <hip/hip_runtime.h>
#include <hip/hip_bf16.h>
#include <math.h>

#define N_NODES 50000
#define E_EDGES 1200000
#define E_TOT   (E_EDGES + N_NODES)
#define NEG_SLOPE 0.2f
#define BN_EPS 1e-5f
#define P_PART 196          // partitions of 256 nodes (dst >> 8)
#define B1 256              // blocks in hist/scatter passes
#define NSCAN (P_PART * B1) // 50176

// wave-uniform lane broadcasts via v_readlane (SGPR path, no LDS/bpermute)
__device__ __forceinline__ int rl_i(int v, int l) {
    return __builtin_amdgcn_readlane(v, l);
}
__device__ __forceinline__ float rl_f(float v, int l) {
    return __uint_as_float(__builtin_amdgcn_readlane(__float_as_uint(v), l));
}
// fp32 -> bf16 bits with round-to-nearest-even
__device__ __forceinline__ unsigned bf16_bits(float f) {
    unsigned u = __float_as_uint(f);
    return (u + 0x7FFFu + ((u >> 16) & 1u)) >> 16;
}

// ==================== atomic-free CSR build (partition sort) =============
__global__ void hist_kernel(const int* __restrict__ edst, unsigned* __restrict__ Ghist) {
    __shared__ unsigned hist[P_PART];
    for (int i = threadIdx.x; i < P_PART; i += 256) hist[i] = 0;
    __syncthreads();
    const int chunk = (E_TOT + B1 - 1) / B1;
    const int beg = blockIdx.x * chunk;
    const int end = min(beg + chunk, E_TOT);
    for (int i = beg + threadIdx.x; i < end; i += 256) {
        int d = (i < E_EDGES) ? edst[i] : (i - E_EDGES);
        atomicAdd(&hist[d >> 8], 1u);          // LDS atomic
    }
    __syncthreads();
    for (int p = threadIdx.x; p < P_PART; p += 256)
        Ghist[p * B1 + blockIdx.x] = hist[p];  // bin-major for scan
}

__global__ void scan2_kernel(const unsigned* __restrict__ Ghist, unsigned* __restrict__ Goff) {
    __shared__ unsigned lds[1024];
    const int t = threadIdx.x;
    const int C = (NSCAN + 1023) / 1024;
    const int beg = t * C;
    const int end = min(beg + C, NSCAN);
    unsigned sum = 0;
    for (int i = beg; i < end; ++i) sum += Ghist[i];
    lds[t] = sum;
    __syncthreads();
    for (int off = 1; off < 1024; off <<= 1) {
        unsigned x = (t >= off) ? lds[t - off] : 0;
        __syncthreads();
        lds[t] += x;
        __syncthreads();
    }
    unsigned run = (t == 0) ? 0 : lds[t - 1];
    for (int i = beg; i < end; ++i) { Goff[i] = run; run += Ghist[i]; }
}

__global__ void partbase_kernel(const unsigned* __restrict__ Goff,
                                int* __restrict__ partbase, int* __restrict__ ptr) {
    int p = threadIdx.x;
    if (p < P_PART) partbase[p] = (int)Goff[p * B1];
    if (p == P_PART) partbase[P_PART] = E_TOT;
    if (p == 0) ptr[N_NODES] = E_TOT;
}

__global__ void scat2_kernel(const int* __restrict__ esrc, const int* __restrict__ edst,
                             const unsigned* __restrict__ Goff, unsigned* __restrict__ Gpart) {
    __shared__ unsigned cur[P_PART];
    for (int p = threadIdx.x; p < P_PART; p += 256) cur[p] = Goff[p * B1 + blockIdx.x];
    __syncthreads();
    const int chunk = (E_TOT + B1 - 1) / B1;
    const int beg = blockIdx.x * chunk;
    const int end = min(beg + chunk, E_TOT);
    for (int i = beg + threadIdx.x; i < end; i += 256) {
        int s = (i < E_EDGES) ? esrc[i] : (i - E_EDGES);
        int d = (i < E_EDGES) ? edst[i] : (i - E_EDGES);
        unsigned slot = atomicAdd(&cur[d >> 8], 1u);   // LDS atomic
        Gpart[slot] = ((unsigned)(d & 255) << 16) | (unsigned)s;
    }
}

// emits csr (src u16) AND dlocal u16 per slot (needed by per-layer ew pass)
__global__ void csr_kernel(const int* __restrict__ partbase, const unsigned* __restrict__ Gpart,
                           int* __restrict__ ptr, unsigned short* __restrict__ csr,
                           unsigned short* __restrict__ dl16) {
    __shared__ unsigned deg[256];
    __shared__ unsigned scn[256];
    const int p = blockIdx.x;
    const int t = threadIdx.x;
    const int base = partbase[p];
    const int cnt = partbase[p + 1] - base;
    deg[t] = 0;
    __syncthreads();
    for (int i = t; i < cnt; i += 256)
        atomicAdd(&deg[Gpart[base + i] >> 16], 1u);
    __syncthreads();
    unsigned v = deg[t];
    scn[t] = v;
    __syncthreads();
    for (int o = 1; o < 256; o <<= 1) {
        unsigned x = (t >= o) ? scn[t - o] : 0;
        __syncthreads();
        scn[t] += x;
        __syncthreads();
    }
    unsigned excl = scn[t] - v;           // exclusive prefix
    int node = p * 256 + t;
    if (node < N_NODES) ptr[node] = base + (int)excl;
    __syncthreads();
    deg[t] = excl;                        // reuse deg[] as cursor
    __syncthreads();
    for (int i = t; i < cnt; i += 256) {
        unsigned rec = Gpart[base + i];
        unsigned dl = rec >> 16;
        unsigned slot = atomicAdd(&deg[dl], 1u);          // LDS atomic
        csr[base + slot]  = (unsigned short)(rec & 0xFFFFu);
        dl16[base + slot] = (unsigned short)dl;
    }
}

// ==================== per-layer edge-weight precompute ===================
// one block per partition (1024 thr): coalesced csr/dlocal reads, random
// asrc gather (L2-resident), adst slice in LDS, exp -> packed record
// {src|w0bf16<<16, w1bf16}; per-node denominator via LDS float atomics.
__global__ void ew_kernel(const int* __restrict__ partbase,
                          const unsigned short* __restrict__ csr,
                          const unsigned short* __restrict__ dl16,
                          const float2* __restrict__ asrc,
                          const float2* __restrict__ adst,
                          uint2* __restrict__ wrec,
                          float2* __restrict__ denom) {
    __shared__ float2 sad[256];
    __shared__ float sden[512];
    const int p = blockIdx.x, t = threadIdx.x;
    if (t < 256) {
        int node = p * 256 + t;
        sad[t] = (node < N_NODES) ? adst[node] : make_float2(0.f, 0.f);
    }
    if (t < 512) sden[t] = 0.f;
    __syncthreads();
    const int base = partbase[p];
    const int cnt = partbase[p + 1] - base;
    for (int i = t; i < cnt; i += 1024) {
        int s  = (int)csr[base + i];
        int dl = (int)dl16[base + i];
        float2 a = asrc[s];
        float2 b = sad[dl];
        float e0 = a.x + b.x; e0 = e0 > 0.f ? e0 : NEG_SLOPE * e0;
        float e1 = a.y + b.y; e1 = e1 > 0.f ? e1 : NEG_SLOPE * e1;
        float w0 = __expf(e0), w1 = __expf(e1);
        atomicAdd(&sden[dl * 2 + 0], w0);     // LDS float atomic
        atomicAdd(&sden[dl * 2 + 1], w1);
        wrec[base + i] = make_uint2((unsigned)s | (bf16_bits(w0) << 16), bf16_bits(w1));
    }
    __syncthreads();
    if (t < 256) {
        int node = p * 256 + t;
        if (node < N_NODES) denom[node] = make_float2(sden[t * 2], sden[t * 2 + 1]);
    }
}

// ==================== h = x @ W  (+ attention coefficients) ==============
template<int K>
__global__ void lin_att_kernel(const float* __restrict__ x,
                               const float* __restrict__ W,
                               const float* __restrict__ a_s,
                               const float* __restrict__ a_d,
                               __hip_bfloat16* __restrict__ h,
                               float* __restrict__ asrc,
                               float* __restrict__ adst,
                               int n) {
    __shared__ float sW[K * 64];
    const int tid = threadIdx.x, lane = tid & 63;
    for (int i = tid; i < K * 64; i += 256) sW[i] = W[i];
    __syncthreads();
    const float a_sv = a_s[lane];
    const float a_dv = a_d[lane];
    const int wid = blockIdx.x * 4 + (tid >> 6);
    const int nwaves = gridDim.x * 4;
    for (int node = wid; node < n; node += nwaves) {
        float xr[K / 64];
        #pragma unroll
        for (int p = 0; p < K / 64; ++p) xr[p] = x[node * K + p * 64 + lane];
        float acc = 0.f;
        #pragma unroll
        for (int p = 0; p < K / 64; ++p) {
            #pragma unroll
            for (int k = 0; k < 64; ++k) {
                float xk = rl_f(xr[p], k);
                acc = fmaf(xk, sW[(p * 64 + k) * 64 + lane], acc);
            }
        }
        h[node * 64 + lane] = __float2bfloat16(acc);
        float ps = acc * a_sv, pd = acc * a_dv;
        #pragma unroll
        for (int m = 1; m < 32; m <<= 1) {
            ps += __shfl_xor(ps, m, 64);
            pd += __shfl_xor(pd, m, 64);
        }
        if ((lane & 31) == 0) {
            asrc[node * 2 + (lane >> 5)] = ps;
            adst[node * 2 + (lane >> 5)] = pd;
        }
    }
}

// ==================== fused GAT aggregate (precomputed weights) ==========
// one wave per dst node; lane = channel. Chunk prologue = ONE coalesced
// 8B load of packed {src,w0,w1}. Per edge: rec.x readlane carries src AND
// w0; uniform-SGPR row pointer -> saddr-form ushort load; 1 fma.
template<bool BN, bool FINAL>
__global__ void gat_agg_kernel(const int* __restrict__ ptr,
                               const uint2* __restrict__ wrec,
                               const float2* __restrict__ denom,
                               const __hip_bfloat16* __restrict__ h,
                               const float* __restrict__ bias,
                               const float* __restrict__ gamma, const float* __restrict__ beta,
                               const float* __restrict__ mean, const float* __restrict__ var,
                               float* __restrict__ out,
                               const float* __restrict__ x1, const float* __restrict__ Wf,
                               const float* __restrict__ bf, float* __restrict__ out40) {
    __shared__ float sWf[FINAL ? 64 * 40 : 1];
    if constexpr (FINAL) {
        for (int i = threadIdx.x; i < 64 * 40; i += 256) sWf[i] = Wf[i];
        __syncthreads();
    }
    int node = blockIdx.x * 4 + (threadIdx.x >> 6);
    if (node >= N_NODES) return;
    const int lane = threadIdx.x & 63;
    const int half = lane & 31;
    const bool lo = (lane < 32);
    float2 dn = denom[node];
    const float den = lo ? dn.x : dn.y;
    float acc = 0.f;
    const int beg = ptr[node], end = ptr[node + 1];

#define EDGE(J) {                                                            \
        unsigned rx = (unsigned)rl_i((int)rec.x, (J));                       \
        unsigned ry = (unsigned)rl_i((int)rec.y, (J));                       \
        const __hip_bfloat16* hp = h + (size_t)(rx & 0xFFFFu) * 64u;         \
        float wv = __uint_as_float(lo ? (rx & 0xFFFF0000u) : (ry << 16));    \
        acc = fmaf(wv, __bfloat162float(hp[lane]), acc); }

    for (int base = beg; base < end; base += 32) {
        const int cnt = min(32, end - base);
        uint2 rec = make_uint2(0u, 0u);
        if (half < cnt) rec = wrec[base + half];
        int j = 0;
        for (; j + 8 <= cnt; j += 8) {
            EDGE(j) EDGE(j + 1) EDGE(j + 2) EDGE(j + 3)
            EDGE(j + 4) EDGE(j + 5) EDGE(j + 6) EDGE(j + 7)
        }
        for (; j < cnt; ++j) { EDGE(j) }
    }
#undef EDGE

    float v = acc / (den + 1e-16f) + bias[lane];
    if constexpr (BN) {
        v = (v - mean[lane]) * rsqrtf(var[lane] + BN_EPS) * gamma[lane] + beta[lane];
        v = v > 0.f ? v : (__expf(v) - 1.f);   // ELU
    }
    if constexpr (FINAL) {
        float jk = fmaxf(x1[node * 64 + lane], v);
        const int o = (lane < 40) ? lane : 0;
        float dot = 0.f;
        #pragma unroll
        for (int c = 0; c < 64; ++c) {
            float jv = rl_f(jk, c);
            dot = fmaf(jv, sWf[c * 40 + o], dot);
        }
        float logit = (lane < 40) ? (dot + bf[o]) : -INFINITY;
        float mx = logit;
        #pragma unroll
        for (int mm = 1; mm < 64; mm <<= 1) mx = fmaxf(mx, __shfl_xor(mx, mm, 64));
        float ex = (lane < 40) ? __expf(logit - mx) : 0.f;
        float sum = ex;
        #pragma unroll
        for (int mm = 1; mm < 64; mm <<= 1) sum += __shfl_xor(sum, mm, 64);
        if (lane < 40) out40[node * 40 + lane] = logit - mx - logf(sum);
    } else {
        out[node * 64 + lane] = v;
    }
}

extern "C" void kernel_launch(void* const* d_in, const int* in_sizes, int n_in,
                              void* d_out, int out_size, void* d_ws, size_t ws_size,
                              hipStream_t stream) {
    const float* x     = (const float*)d_in[0];
    const int*   ei    = (const int*)d_in[1];
    const float* W1    = (const float*)d_in[2];
    const float* as1   = (const float*)d_in[3];
    const float* ad1   = (const float*)d_in[4];
    const float* b1    = (const float*)d_in[5];
    const float* gamma = (const float*)d_in[6];
    const float* beta  = (const float*)d_in[7];
    const float* mean  = (const float*)d_in[8];
    const float* var   = (const float*)d_in[9];
    const float* W2    = (const float*)d_in[10];
    const float* as2   = (const float*)d_in[11];
    const float* ad2   = (const float*)d_in[12];
    const float* b2    = (const float*)d_in[13];
    const float* Wf    = (const float*)d_in[14];
    const float* bf    = (const float*)d_in[15];
    float* out = (float*)d_out;
    const int* esrc = ei;
    const int* edst = ei + E_EDGES;

    char* ws = (char*)d_ws;
    size_t off = 0;
    auto alloc = [&](size_t bytes) {
        char* p = ws + off;
        off += (bytes + 255) & ~(size_t)255;
        return p;
    };
    unsigned* Ghist = (unsigned*)alloc((size_t)NSCAN * 4);
    unsigned* Goff  = (unsigned*)alloc((size_t)NSCAN * 4);
    int* partbase   = (int*)alloc((size_t)(P_PART + 1) * 4);
    unsigned* Gpart = (unsigned*)alloc((size_t)E_TOT * 4);
    int* ptr              = (int*)alloc((size_t)(N_NODES + 1) * 4);
    unsigned short* csr   = (unsigned short*)alloc((size_t)E_TOT * 2);
    unsigned short* dl16  = (unsigned short*)alloc((size_t)E_TOT * 2);
    uint2* wrec           = (uint2*)alloc((size_t)E_TOT * 8);
    float2* denom         = (float2*)alloc((size_t)N_NODES * 8);
    __hip_bfloat16* hbuf  = (__hip_bfloat16*)alloc((size_t)N_NODES * 64 * 2);
    float* x1buf = (float*)alloc((size_t)N_NODES * 64 * 4);
    float* asrc  = (float*)alloc((size_t)N_NODES * 2 * 4);
    float* adst  = (float*)alloc((size_t)N_NODES * 2 * 4);
    (void)ws_size; (void)in_sizes; (void)n_in; (void)out_size;

    const int NB = (N_NODES + 3) / 4;

    // ---------- CSR build (atomic-free partition sort, once) ----------
    hist_kernel<<<B1, 256, 0, stream>>>(edst, Ghist);
    scan2_kernel<<<1, 1024, 0, stream>>>(Ghist, Goff);
    partbase_kernel<<<1, 256, 0, stream>>>(Goff, partbase, ptr);
    scat2_kernel<<<B1, 256, 0, stream>>>(esrc, edst, Goff, Gpart);
    csr_kernel<<<P_PART, 256, 0, stream>>>(partbase, Gpart, ptr, csr, dl16);

    // ---------- layer 1 ----------
    lin_att_kernel<128><<<2048, 256, 0, stream>>>(x, W1, as1, ad1, hbuf, asrc, adst, N_NODES);
    ew_kernel<<<P_PART, 1024, 0, stream>>>(partbase, csr, dl16,
        (const float2*)asrc, (const float2*)adst, wrec, denom);
    gat_agg_kernel<true, false><<<NB, 256, 0, stream>>>(ptr, wrec, denom, hbuf,
        b1, gamma, beta, mean, var, x1buf, nullptr, nullptr, nullptr, nullptr);

    // ---------- layer 2 (+ fused JK + final linear + log_softmax) ----------
    lin_att_kernel<64><<<2048, 256, 0, stream>>>(x1buf, W2, as2, ad2, hbuf, asrc, adst, N_NODES);
    ew_kernel<<<P_PART, 1024, 0, stream>>>(partbase, csr, dl16,
        (const float2*)asrc, (const float2*)adst, wrec, denom);
    gat_agg_kernel<false, true><<<NB, 256, 0, stream>>>(ptr, wrec, denom, hbuf,
        b2, nullptr, nullptr, nullptr, nullptr, nullptr, x1buf, Wf, bf, out);
}

// Round 15
// 269.402 us; speedup vs baseline: 1.0783x; 1.0783x over previous
//
#include <hip/hip_runtime.h>
#include <hip/hip_bf16.h>
#include <math.h>

#define N_NODES 50000
#define E_EDGES 1200000
#define E_TOT   (E_EDGES + N_NODES)
#define NEG_SLOPE 0.2f
#define BN_EPS 1e-5f
#define P_PART 196          // partitions of 256 nodes (dst >> 8)
#define B1 256              // blocks in hist/scatter passes
#define NSCAN (P_PART * B1) // 50176

// wave-uniform lane broadcasts via v_readlane (SGPR path, no LDS/bpermute)
__device__ __forceinline__ int rl_i(int v, int l) {
    return __builtin_amdgcn_readlane(v, l);
}
__device__ __forceinline__ float rl_f(float v, int l) {
    return __uint_as_float(__builtin_amdgcn_readlane(__float_as_uint(v), l));
}
// fp32 -> bf16 bits with round-to-nearest-even
__device__ __forceinline__ unsigned bf16_bits(float f) {
    unsigned u = __float_as_uint(f);
    return (u + 0x7FFFu + ((u >> 16) & 1u)) >> 16;
}

// ==================== atomic-free CSR build (partition sort) =============
__global__ void hist_kernel(const int* __restrict__ edst, unsigned* __restrict__ Ghist) {
    __shared__ unsigned hist[P_PART];
    for (int i = threadIdx.x; i < P_PART; i += 256) hist[i] = 0;
    __syncthreads();
    const int chunk = (E_TOT + B1 - 1) / B1;
    const int beg = blockIdx.x * chunk;
    const int end = min(beg + chunk, E_TOT);
    for (int i = beg + threadIdx.x; i < end; i += 256) {
        int d = (i < E_EDGES) ? edst[i] : (i - E_EDGES);
        atomicAdd(&hist[d >> 8], 1u);          // LDS atomic
    }
    __syncthreads();
    for (int p = threadIdx.x; p < P_PART; p += 256)
        Ghist[p * B1 + blockIdx.x] = hist[p];  // bin-major for scan
}

__global__ void scan2_kernel(const unsigned* __restrict__ Ghist, unsigned* __restrict__ Goff) {
    __shared__ unsigned lds[1024];
    const int t = threadIdx.x;
    const int C = (NSCAN + 1023) / 1024;
    const int beg = t * C;
    const int end = min(beg + C, NSCAN);
    unsigned sum = 0;
    for (int i = beg; i < end; ++i) sum += Ghist[i];
    lds[t] = sum;
    __syncthreads();
    for (int off = 1; off < 1024; off <<= 1) {
        unsigned x = (t >= off) ? lds[t - off] : 0;
        __syncthreads();
        lds[t] += x;
        __syncthreads();
    }
    unsigned run = (t == 0) ? 0 : lds[t - 1];
    for (int i = beg; i < end; ++i) { Goff[i] = run; run += Ghist[i]; }
}

__global__ void partbase_kernel(const unsigned* __restrict__ Goff,
                                int* __restrict__ partbase, int* __restrict__ ptr) {
    int p = threadIdx.x;
    if (p < P_PART) partbase[p] = (int)Goff[p * B1];
    if (p == P_PART) partbase[P_PART] = E_TOT;
    if (p == 0) ptr[N_NODES] = E_TOT;
}

__global__ void scat2_kernel(const int* __restrict__ esrc, const int* __restrict__ edst,
                             const unsigned* __restrict__ Goff, unsigned* __restrict__ Gpart) {
    __shared__ unsigned cur[P_PART];
    for (int p = threadIdx.x; p < P_PART; p += 256) cur[p] = Goff[p * B1 + blockIdx.x];
    __syncthreads();
    const int chunk = (E_TOT + B1 - 1) / B1;
    const int beg = blockIdx.x * chunk;
    const int end = min(beg + chunk, E_TOT);
    for (int i = beg + threadIdx.x; i < end; i += 256) {
        int s = (i < E_EDGES) ? esrc[i] : (i - E_EDGES);
        int d = (i < E_EDGES) ? edst[i] : (i - E_EDGES);
        unsigned slot = atomicAdd(&cur[d >> 8], 1u);   // LDS atomic
        Gpart[slot] = ((unsigned)(d & 255) << 16) | (unsigned)s;
    }
}

// emits csr (src u16) AND dlocal u16 per slot (needed by per-layer ew pass)
__global__ void csr_kernel(const int* __restrict__ partbase, const unsigned* __restrict__ Gpart,
                           int* __restrict__ ptr, unsigned short* __restrict__ csr,
                           unsigned short* __restrict__ dl16) {
    __shared__ unsigned deg[256];
    __shared__ unsigned scn[256];
    const int p = blockIdx.x;
    const int t = threadIdx.x;
    const int base = partbase[p];
    const int cnt = partbase[p + 1] - base;
    deg[t] = 0;
    __syncthreads();
    for (int i = t; i < cnt; i += 256)
        atomicAdd(&deg[Gpart[base + i] >> 16], 1u);
    __syncthreads();
    unsigned v = deg[t];
    scn[t] = v;
    __syncthreads();
    for (int o = 1; o < 256; o <<= 1) {
        unsigned x = (t >= o) ? scn[t - o] : 0;
        __syncthreads();
        scn[t] += x;
        __syncthreads();
    }
    unsigned excl = scn[t] - v;           // exclusive prefix
    int node = p * 256 + t;
    if (node < N_NODES) ptr[node] = base + (int)excl;
    __syncthreads();
    deg[t] = excl;                        // reuse deg[] as cursor
    __syncthreads();
    for (int i = t; i < cnt; i += 256) {
        unsigned rec = Gpart[base + i];
        unsigned dl = rec >> 16;
        unsigned slot = atomicAdd(&deg[dl], 1u);          // LDS atomic
        csr[base + slot]  = (unsigned short)(rec & 0xFFFFu);
        dl16[base + slot] = (unsigned short)dl;
    }
}

// ==================== per-layer edge-weight precompute ===================
__global__ void ew_kernel(const int* __restrict__ partbase,
                          const unsigned short* __restrict__ csr,
                          const unsigned short* __restrict__ dl16,
                          const float2* __restrict__ asrc,
                          const float2* __restrict__ adst,
                          uint2* __restrict__ wrec,
                          float2* __restrict__ denom) {
    __shared__ float2 sad[256];
    __shared__ float sden[512];
    const int p = blockIdx.x, t = threadIdx.x;
    if (t < 256) {
        int node = p * 256 + t;
        sad[t] = (node < N_NODES) ? adst[node] : make_float2(0.f, 0.f);
    }
    if (t < 512) sden[t] = 0.f;
    __syncthreads();
    const int base = partbase[p];
    const int cnt = partbase[p + 1] - base;
    for (int i = t; i < cnt; i += 1024) {
        int s  = (int)csr[base + i];
        int dl = (int)dl16[base + i];
        float2 a = asrc[s];
        float2 b = sad[dl];
        float e0 = a.x + b.x; e0 = e0 > 0.f ? e0 : NEG_SLOPE * e0;
        float e1 = a.y + b.y; e1 = e1 > 0.f ? e1 : NEG_SLOPE * e1;
        float w0 = __expf(e0), w1 = __expf(e1);
        atomicAdd(&sden[dl * 2 + 0], w0);     // LDS float atomic
        atomicAdd(&sden[dl * 2 + 1], w1);
        wrec[base + i] = make_uint2((unsigned)s | (bf16_bits(w0) << 16), bf16_bits(w1));
    }
    __syncthreads();
    if (t < 256) {
        int node = p * 256 + t;
        if (node < N_NODES) denom[node] = make_float2(sden[t * 2], sden[t * 2 + 1]);
    }
}

// ==================== h = x @ W : register-tiled GEMM ====================
// block = 256 thr computes a 64-node x 64-channel tile; thread owns a
// 4x4 register tile (nodes ng*4.., channels cg*4..). Per k: 1 ds_read_b128
// (W) + 4 broadcast ds_read_b32 (x, stride K+1 pad) + 16 independent FMAs.
// Epilogue: bf16 ushort4 h-store; a_s/a_d partials reduced over the 8
// cg-lanes of each head via 3-step shfl_xor -> asrc/adst.
template<int K>
__global__ __launch_bounds__(256) void lin_att_kernel(
        const float* __restrict__ x, const float* __restrict__ W,
        const float* __restrict__ a_s, const float* __restrict__ a_d,
        __hip_bfloat16* __restrict__ h, float* __restrict__ asrc,
        float* __restrict__ adst) {
    __shared__ float sx[64 * (K + 1)];
    __shared__ float sW[K * 64];
    const int tid = threadIdx.x;
    for (int i = tid; i < K * 64; i += 256) sW[i] = W[i];
    const int ng = tid >> 4;          // node group 0..15 -> nodes ng*4..+3
    const int cg = tid & 15;          // channel group -> channels cg*4..+3
    const int c0 = cg * 4;
    const float4 asv = *(const float4*)&a_s[c0];
    const float4 adv = *(const float4*)&a_d[c0];
    const int ntiles = (N_NODES + 63) / 64;
    for (int tile = blockIdx.x; tile < ntiles; tile += gridDim.x) {
        const int nbase = tile * 64;
        __syncthreads();
        for (int i = tid; i < 64 * K; i += 256) {
            int n = i / K, k = i - n * K;
            int node = nbase + n;
            sx[n * (K + 1) + k] = (node < N_NODES) ? x[(size_t)node * K + k] : 0.f;
        }
        __syncthreads();
        float acc[4][4] = {};
        #pragma unroll 4
        for (int k = 0; k < K; ++k) {
            float4 wv = *(const float4*)&sW[k * 64 + c0];
            #pragma unroll
            for (int j = 0; j < 4; ++j) {
                float xv = sx[(ng * 4 + j) * (K + 1) + k];
                acc[j][0] = fmaf(xv, wv.x, acc[j][0]);
                acc[j][1] = fmaf(xv, wv.y, acc[j][1]);
                acc[j][2] = fmaf(xv, wv.z, acc[j][2]);
                acc[j][3] = fmaf(xv, wv.w, acc[j][3]);
            }
        }
        #pragma unroll
        for (int j = 0; j < 4; ++j) {
            int node = nbase + ng * 4 + j;
            float ps = acc[j][0] * asv.x + acc[j][1] * asv.y +
                       acc[j][2] * asv.z + acc[j][3] * asv.w;
            float pd = acc[j][0] * adv.x + acc[j][1] * adv.y +
                       acc[j][2] * adv.z + acc[j][3] * adv.w;
            // reduce over the 8 cg-lanes of this head (lane bits 0..2)
            #pragma unroll
            for (int o = 1; o < 8; o <<= 1) {
                ps += __shfl_xor(ps, o, 64);
                pd += __shfl_xor(pd, o, 64);
            }
            if (node < N_NODES) {
                ushort4 pk;
                pk.x = (unsigned short)bf16_bits(acc[j][0]);
                pk.y = (unsigned short)bf16_bits(acc[j][1]);
                pk.z = (unsigned short)bf16_bits(acc[j][2]);
                pk.w = (unsigned short)bf16_bits(acc[j][3]);
                *(ushort4*)&h[(size_t)node * 64 + c0] = pk;
                if ((cg & 7) == 0) {
                    int head = cg >> 3;
                    asrc[node * 2 + head] = ps;
                    adst[node * 2 + head] = pd;
                }
            }
        }
    }
}

// ==================== fused GAT aggregate (precomputed weights) ==========
template<bool BN, bool FINAL>
__global__ void gat_agg_kernel(const int* __restrict__ ptr,
                               const uint2* __restrict__ wrec,
                               const float2* __restrict__ denom,
                               const __hip_bfloat16* __restrict__ h,
                               const float* __restrict__ bias,
                               const float* __restrict__ gamma, const float* __restrict__ beta,
                               const float* __restrict__ mean, const float* __restrict__ var,
                               float* __restrict__ out,
                               const float* __restrict__ x1, const float* __restrict__ Wf,
                               const float* __restrict__ bf, float* __restrict__ out40) {
    __shared__ float sWf[FINAL ? 64 * 40 : 1];
    if constexpr (FINAL) {
        for (int i = threadIdx.x; i < 64 * 40; i += 256) sWf[i] = Wf[i];
        __syncthreads();
    }
    int node = blockIdx.x * 4 + (threadIdx.x >> 6);
    if (node >= N_NODES) return;
    const int lane = threadIdx.x & 63;
    const int half = lane & 31;
    const bool lo = (lane < 32);
    float2 dn = denom[node];
    const float den = lo ? dn.x : dn.y;
    float acc = 0.f;
    const int beg = ptr[node], end = ptr[node + 1];

#define EDGE(J) {                                                            \
        unsigned rx = (unsigned)rl_i((int)rec.x, (J));                       \
        unsigned ry = (unsigned)rl_i((int)rec.y, (J));                       \
        const __hip_bfloat16* hp = h + (size_t)(rx & 0xFFFFu) * 64u;         \
        float wv = __uint_as_float(lo ? (rx & 0xFFFF0000u) : (ry << 16));    \
        acc = fmaf(wv, __bfloat162float(hp[lane]), acc); }

    for (int base = beg; base < end; base += 32) {
        const int cnt = min(32, end - base);
        uint2 rec = make_uint2(0u, 0u);
        if (half < cnt) rec = wrec[base + half];
        int j = 0;
        for (; j + 8 <= cnt; j += 8) {
            EDGE(j) EDGE(j + 1) EDGE(j + 2) EDGE(j + 3)
            EDGE(j + 4) EDGE(j + 5) EDGE(j + 6) EDGE(j + 7)
        }
        for (; j < cnt; ++j) { EDGE(j) }
    }
#undef EDGE

    float v = acc / (den + 1e-16f) + bias[lane];
    if constexpr (BN) {
        v = (v - mean[lane]) * rsqrtf(var[lane] + BN_EPS) * gamma[lane] + beta[lane];
        v = v > 0.f ? v : (__expf(v) - 1.f);   // ELU
    }
    if constexpr (FINAL) {
        float jk = fmaxf(x1[node * 64 + lane], v);
        const int o = (lane < 40) ? lane : 0;
        float dot = 0.f;
        #pragma unroll
        for (int c = 0; c < 64; ++c) {
            float jv = rl_f(jk, c);
            dot = fmaf(jv, sWf[c * 40 + o], dot);
        }
        float logit = (lane < 40) ? (dot + bf[o]) : -INFINITY;
        float mx = logit;
        #pragma unroll
        for (int mm = 1; mm < 64; mm <<= 1) mx = fmaxf(mx, __shfl_xor(mx, mm, 64));
        float ex = (lane < 40) ? __expf(logit - mx) : 0.f;
        float sum = ex;
        #pragma unroll
        for (int mm = 1; mm < 64; mm <<= 1) sum += __shfl_xor(sum, mm, 64);
        if (lane < 40) out40[node * 40 + lane] = logit - mx - logf(sum);
    } else {
        out[node * 64 + lane] = v;
    }
}

extern "C" void kernel_launch(void* const* d_in, const int* in_sizes, int n_in,
                              void* d_out, int out_size, void* d_ws, size_t ws_size,
                              hipStream_t stream) {
    const float* x     = (const float*)d_in[0];
    const int*   ei    = (const int*)d_in[1];
    const float* W1    = (const float*)d_in[2];
    const float* as1   = (const float*)d_in[3];
    const float* ad1   = (const float*)d_in[4];
    const float* b1    = (const float*)d_in[5];
    const float* gamma = (const float*)d_in[6];
    const float* beta  = (const float*)d_in[7];
    const float* mean  = (const float*)d_in[8];
    const float* var   = (const float*)d_in[9];
    const float* W2    = (const float*)d_in[10];
    const float* as2   = (const float*)d_in[11];
    const float* ad2   = (const float*)d_in[12];
    const float* b2    = (const float*)d_in[13];
    const float* Wf    = (const float*)d_in[14];
    const float* bf    = (const float*)d_in[15];
    float* out = (float*)d_out;
    const int* esrc = ei;
    const int* edst = ei + E_EDGES;

    char* ws = (char*)d_ws;
    size_t off = 0;
    auto alloc = [&](size_t bytes) {
        char* p = ws + off;
        off += (bytes + 255) & ~(size_t)255;
        return p;
    };
    unsigned* Ghist = (unsigned*)alloc((size_t)NSCAN * 4);
    unsigned* Goff  = (unsigned*)alloc((size_t)NSCAN * 4);
    int* partbase   = (int*)alloc((size_t)(P_PART + 1) * 4);
    unsigned* Gpart = (unsigned*)alloc((size_t)E_TOT * 4);
    int* ptr              = (int*)alloc((size_t)(N_NODES + 1) * 4);
    unsigned short* csr   = (unsigned short*)alloc((size_t)E_TOT * 2);
    unsigned short* dl16  = (unsigned short*)alloc((size_t)E_TOT * 2);
    uint2* wrec           = (uint2*)alloc((size_t)E_TOT * 8);
    float2* denom         = (float2*)alloc((size_t)N_NODES * 8);
    __hip_bfloat16* hbuf  = (__hip_bfloat16*)alloc((size_t)N_NODES * 64 * 2);
    float* x1buf = (float*)alloc((size_t)N_NODES * 64 * 4);
    float* asrc  = (float*)alloc((size_t)N_NODES * 2 * 4);
    float* adst  = (float*)alloc((size_t)N_NODES * 2 * 4);
    (void)ws_size; (void)in_sizes; (void)n_in; (void)out_size;

    const int NB = (N_NODES + 3) / 4;
    const int GT = (N_NODES + 63) / 64;   // GEMM tiles

    // ---------- CSR build (atomic-free partition sort, once) ----------
    hist_kernel<<<B1, 256, 0, stream>>>(edst, Ghist);
    scan2_kernel<<<1, 1024, 0, stream>>>(Ghist, Goff);
    partbase_kernel<<<1, 256, 0, stream>>>(Goff, partbase, ptr);
    scat2_kernel<<<B1, 256, 0, stream>>>(esrc, edst, Goff, Gpart);
    csr_kernel<<<P_PART, 256, 0, stream>>>(partbase, Gpart, ptr, csr, dl16);

    // ---------- layer 1 ----------
    lin_att_kernel<128><<<GT, 256, 0, stream>>>(x, W1, as1, ad1, hbuf, asrc, adst);
    ew_kernel<<<P_PART, 1024, 0, stream>>>(partbase, csr, dl16,
        (const float2*)asrc, (const float2*)adst, wrec, denom);
    gat_agg_kernel<true, false><<<NB, 256, 0, stream>>>(ptr, wrec, denom, hbuf,
        b1, gamma, beta, mean, var, x1buf, nullptr, nullptr, nullptr, nullptr);

    // ---------- layer 2 (+ fused JK + final linear + log_softmax) ----------
    lin_att_kernel<64><<<GT, 256, 0, stream>>>(x1buf, W2, as2, ad2, hbuf, asrc, adst);
    ew_kernel<<<P_PART, 1024, 0, stream>>>(partbase, csr, dl16,
        (const float2*)asrc, (const float2*)adst, wrec, denom);
    gat_agg_kernel<false, true><<<NB, 256, 0, stream>>>(ptr, wrec, denom, hbuf,
        b2, nullptr, nullptr, nullptr, nullptr, nullptr, x1buf, Wf, bf, out);
}

// Round 16
// 261.039 us; speedup vs baseline: 1.1129x; 1.0320x over previous
//
#include <hip/hip_runtime.h>
#include <hip/hip_bf16.h>
#include <math.h>

#define N_NODES 50000
#define E_EDGES 1200000
#define E_TOT   (E_EDGES + N_NODES)
#define NEG_SLOPE 0.2f
#define BN_EPS 1e-5f
#define P_PART 196          // partitions of 256 nodes (dst >> 8)
#define B1 64               // blocks in hist/scatter passes
#define NSCAN (P_PART * B1) // 12544

// wave-uniform lane broadcasts via v_readlane (SGPR path, no LDS/bpermute)
__device__ __forceinline__ int rl_i(int v, int l) {
    return __builtin_amdgcn_readlane(v, l);
}
__device__ __forceinline__ float rl_f(float v, int l) {
    return __uint_as_float(__builtin_amdgcn_readlane(__float_as_uint(v), l));
}
// fp32 -> bf16 bits with round-to-nearest-even
__device__ __forceinline__ unsigned bf16_bits(float f) {
    unsigned u = __float_as_uint(f);
    return (u + 0x7FFFu + ((u >> 16) & 1u)) >> 16;
}

// ==================== atomic-free CSR build (partition sort) =============
__global__ void hist_kernel(const int* __restrict__ edst, unsigned* __restrict__ Ghist) {
    __shared__ unsigned hist[P_PART];
    for (int i = threadIdx.x; i < P_PART; i += 256) hist[i] = 0;
    __syncthreads();
    const int chunk = (E_TOT + B1 - 1) / B1;
    const int beg = blockIdx.x * chunk;
    const int end = min(beg + chunk, E_TOT);
    for (int i = beg + threadIdx.x; i < end; i += 256) {
        int d = (i < E_EDGES) ? edst[i] : (i - E_EDGES);
        atomicAdd(&hist[d >> 8], 1u);          // LDS atomic
    }
    __syncthreads();
    for (int p = threadIdx.x; p < P_PART; p += 256)
        Ghist[p * B1 + blockIdx.x] = hist[p];  // bin-major for scan
}

__global__ void scan2_kernel(const unsigned* __restrict__ Ghist, unsigned* __restrict__ Goff) {
    __shared__ unsigned lds[1024];
    const int t = threadIdx.x;
    const int C = (NSCAN + 1023) / 1024;
    const int beg = t * C;
    const int end = min(beg + C, NSCAN);
    unsigned sum = 0;
    for (int i = beg; i < end; ++i) sum += Ghist[i];
    lds[t] = sum;
    __syncthreads();
    for (int off = 1; off < 1024; off <<= 1) {
        unsigned x = (t >= off) ? lds[t - off] : 0;
        __syncthreads();
        lds[t] += x;
        __syncthreads();
    }
    unsigned run = (t == 0) ? 0 : lds[t - 1];
    for (int i = beg; i < end; ++i) { Goff[i] = run; run += Ghist[i]; }
}

__global__ void partbase_kernel(const unsigned* __restrict__ Goff,
                                int* __restrict__ partbase, int* __restrict__ ptr) {
    int p = threadIdx.x;
    if (p < P_PART) partbase[p] = (int)Goff[p * B1];
    if (p == P_PART) partbase[P_PART] = E_TOT;
    if (p == 0) ptr[N_NODES] = E_TOT;
}

__global__ void scat2_kernel(const int* __restrict__ esrc, const int* __restrict__ edst,
                             const unsigned* __restrict__ Goff, unsigned* __restrict__ Gpart) {
    __shared__ unsigned cur[P_PART];
    for (int p = threadIdx.x; p < P_PART; p += 256) cur[p] = Goff[p * B1 + blockIdx.x];
    __syncthreads();
    const int chunk = (E_TOT + B1 - 1) / B1;
    const int beg = blockIdx.x * chunk;
    const int end = min(beg + chunk, E_TOT);
    for (int i = beg + threadIdx.x; i < end; i += 256) {
        int s = (i < E_EDGES) ? esrc[i] : (i - E_EDGES);
        int d = (i < E_EDGES) ? edst[i] : (i - E_EDGES);
        unsigned slot = atomicAdd(&cur[d >> 8], 1u);   // LDS atomic
        Gpart[slot] = ((unsigned)(d & 255) << 16) | (unsigned)s;
    }
}

// sorts within partition by node; emits srec u32 = (dlocal<<16 | src)
__global__ void csr_kernel(const int* __restrict__ partbase, const unsigned* __restrict__ Gpart,
                           int* __restrict__ ptr, unsigned* __restrict__ srec) {
    __shared__ unsigned deg[256];
    __shared__ unsigned scn[256];
    const int p = blockIdx.x;
    const int t = threadIdx.x;
    const int base = partbase[p];
    const int cnt = partbase[p + 1] - base;
    deg[t] = 0;
    __syncthreads();
    for (int i = t; i < cnt; i += 256)
        atomicAdd(&deg[Gpart[base + i] >> 16], 1u);
    __syncthreads();
    unsigned v = deg[t];
    scn[t] = v;
    __syncthreads();
    for (int o = 1; o < 256; o <<= 1) {
        unsigned x = (t >= o) ? scn[t - o] : 0;
        __syncthreads();
        scn[t] += x;
        __syncthreads();
    }
    unsigned excl = scn[t] - v;           // exclusive prefix
    int node = p * 256 + t;
    if (node < N_NODES) ptr[node] = base + (int)excl;
    __syncthreads();
    deg[t] = excl;                        // reuse deg[] as cursor
    __syncthreads();
    for (int i = t; i < cnt; i += 256) {
        unsigned rec = Gpart[base + i];
        unsigned slot = atomicAdd(&deg[rec >> 16], 1u);   // LDS atomic
        srec[base + slot] = rec;
    }
}

// ==================== per-layer edge-weight precompute ===================
// 4 blocks per partition (no cross-thread state needed since denominator
// moved into gat_agg). wrec = {src, w0bf16 | w1bf16<<16}.
__global__ void ew_kernel(const int* __restrict__ partbase,
                          const unsigned* __restrict__ srec,
                          const float2* __restrict__ asrc,
                          const float2* __restrict__ adst,
                          uint2* __restrict__ wrec) {
    __shared__ float2 sad[256];
    const int p = blockIdx.x >> 2, q = blockIdx.x & 3;
    const int t = threadIdx.x;
    {
        int node = p * 256 + t;
        sad[t] = (node < N_NODES) ? adst[node] : make_float2(0.f, 0.f);
    }
    __syncthreads();
    const int base = partbase[p];
    const int cnt = partbase[p + 1] - base;
    const int qbeg = base + (cnt * q) / 4;
    const int qend = base + (cnt * (q + 1)) / 4;
    for (int i = qbeg + t; i < qend; i += 256) {
        unsigned rec = srec[i];
        int s  = (int)(rec & 0xFFFFu);
        int dl = (int)(rec >> 16);
        float2 a = asrc[s];
        float2 b = sad[dl];
        float e0 = a.x + b.x; e0 = e0 > 0.f ? e0 : NEG_SLOPE * e0;
        float e1 = a.y + b.y; e1 = e1 > 0.f ? e1 : NEG_SLOPE * e1;
        wrec[i] = make_uint2((unsigned)s,
                             bf16_bits(__expf(e0)) | (bf16_bits(__expf(e1)) << 16));
    }
}

// ==================== h = x @ W : register-tiled GEMM ====================
template<int K>
__global__ __launch_bounds__(256) void lin_att_kernel(
        const float* __restrict__ x, const float* __restrict__ W,
        const float* __restrict__ a_s, const float* __restrict__ a_d,
        __hip_bfloat16* __restrict__ h, float* __restrict__ asrc,
        float* __restrict__ adst) {
    __shared__ float sx[64 * (K + 1)];
    __shared__ float sW[K * 64];
    const int tid = threadIdx.x;
    for (int i = tid; i < K * 64; i += 256) sW[i] = W[i];
    const int ng = tid >> 4;          // node group 0..15 -> nodes ng*4..+3
    const int cg = tid & 15;          // channel group -> channels cg*4..+3
    const int c0 = cg * 4;
    const float4 asv = *(const float4*)&a_s[c0];
    const float4 adv = *(const float4*)&a_d[c0];
    const int ntiles = (N_NODES + 63) / 64;
    for (int tile = blockIdx.x; tile < ntiles; tile += gridDim.x) {
        const int nbase = tile * 64;
        __syncthreads();
        for (int i = tid; i < 64 * K; i += 256) {
            int n = i / K, k = i - n * K;
            int node = nbase + n;
            sx[n * (K + 1) + k] = (node < N_NODES) ? x[(size_t)node * K + k] : 0.f;
        }
        __syncthreads();
        float acc[4][4] = {};
        #pragma unroll 4
        for (int k = 0; k < K; ++k) {
            float4 wv = *(const float4*)&sW[k * 64 + c0];
            #pragma unroll
            for (int j = 0; j < 4; ++j) {
                float xv = sx[(ng * 4 + j) * (K + 1) + k];
                acc[j][0] = fmaf(xv, wv.x, acc[j][0]);
                acc[j][1] = fmaf(xv, wv.y, acc[j][1]);
                acc[j][2] = fmaf(xv, wv.z, acc[j][2]);
                acc[j][3] = fmaf(xv, wv.w, acc[j][3]);
            }
        }
        #pragma unroll
        for (int j = 0; j < 4; ++j) {
            int node = nbase + ng * 4 + j;
            float ps = acc[j][0] * asv.x + acc[j][1] * asv.y +
                       acc[j][2] * asv.z + acc[j][3] * asv.w;
            float pd = acc[j][0] * adv.x + acc[j][1] * adv.y +
                       acc[j][2] * adv.z + acc[j][3] * adv.w;
            #pragma unroll
            for (int o = 1; o < 8; o <<= 1) {
                ps += __shfl_xor(ps, o, 64);
                pd += __shfl_xor(pd, o, 64);
            }
            if (node < N_NODES) {
                ushort4 pk;
                pk.x = (unsigned short)bf16_bits(acc[j][0]);
                pk.y = (unsigned short)bf16_bits(acc[j][1]);
                pk.z = (unsigned short)bf16_bits(acc[j][2]);
                pk.w = (unsigned short)bf16_bits(acc[j][3]);
                *(ushort4*)&h[(size_t)node * 64 + c0] = pk;
                if ((cg & 7) == 0) {
                    int head = cg >> 3;
                    asrc[node * 2 + head] = ps;
                    adst[node * 2 + head] = pd;
                }
            }
        }
    }
}

// ==================== fused GAT aggregate (precomputed weights) ==========
// one wave per dst node. Per edge: 2 readlane, wv = (ry<<shl)&0xFFFF0000
// (2 VALU), saddr ushort load, cvt, fma, s += wv. Denominator falls out
// of the broadcast loop for free (every lane sees every edge's w).
template<bool BN, bool FINAL>
__global__ void gat_agg_kernel(const int* __restrict__ ptr,
                               const uint2* __restrict__ wrec,
                               const __hip_bfloat16* __restrict__ h,
                               const float* __restrict__ bias,
                               const float* __restrict__ gamma, const float* __restrict__ beta,
                               const float* __restrict__ mean, const float* __restrict__ var,
                               float* __restrict__ out,
                               const float* __restrict__ x1, const float* __restrict__ Wf,
                               const float* __restrict__ bf, float* __restrict__ out40) {
    __shared__ float sWf[FINAL ? 64 * 40 : 1];
    if constexpr (FINAL) {
        for (int i = threadIdx.x; i < 64 * 40; i += 256) sWf[i] = Wf[i];
        __syncthreads();
    }
    int node = blockIdx.x * 4 + (threadIdx.x >> 6);
    if (node >= N_NODES) return;
    const int lane = threadIdx.x & 63;
    const int half = lane & 31;
    const unsigned shl = (lane < 32) ? 16u : 0u;   // per-lane VGPR shift
    float acc = 0.f, s = 0.f;
    const int beg = ptr[node], end = ptr[node + 1];

#define EDGE(J) {                                                            \
        unsigned rx = (unsigned)rl_i((int)rec.x, (J));                       \
        unsigned ry = (unsigned)rl_i((int)rec.y, (J));                       \
        const __hip_bfloat16* hp = h + (size_t)rx * 64u;                     \
        float wv = __uint_as_float((ry << shl) & 0xFFFF0000u);               \
        acc = fmaf(wv, __bfloat162float(hp[lane]), acc);                     \
        s += wv; }

    for (int base = beg; base < end; base += 32) {
        const int cnt = min(32, end - base);
        uint2 rec = make_uint2(0u, 0u);
        if (half < cnt) rec = wrec[base + half];
        int j = 0;
        for (; j + 8 <= cnt; j += 8) {
            EDGE(j) EDGE(j + 1) EDGE(j + 2) EDGE(j + 3)
            EDGE(j + 4) EDGE(j + 5) EDGE(j + 6) EDGE(j + 7)
        }
        for (; j < cnt; ++j) { EDGE(j) }
    }
#undef EDGE

    float v = acc / (s + 1e-16f) + bias[lane];
    if constexpr (BN) {
        v = (v - mean[lane]) * rsqrtf(var[lane] + BN_EPS) * gamma[lane] + beta[lane];
        v = v > 0.f ? v : (__expf(v) - 1.f);   // ELU
    }
    if constexpr (FINAL) {
        float jk = fmaxf(x1[node * 64 + lane], v);
        const int o = (lane < 40) ? lane : 0;
        float dot = 0.f;
        #pragma unroll
        for (int c = 0; c < 64; ++c) {
            float jv = rl_f(jk, c);
            dot = fmaf(jv, sWf[c * 40 + o], dot);
        }
        float logit = (lane < 40) ? (dot + bf[o]) : -INFINITY;
        float mx = logit;
        #pragma unroll
        for (int mm = 1; mm < 64; mm <<= 1) mx = fmaxf(mx, __shfl_xor(mx, mm, 64));
        float ex = (lane < 40) ? __expf(logit - mx) : 0.f;
        float sum = ex;
        #pragma unroll
        for (int mm = 1; mm < 64; mm <<= 1) sum += __shfl_xor(sum, mm, 64);
        if (lane < 40) out40[node * 40 + lane] = logit - mx - logf(sum);
    } else {
        out[node * 64 + lane] = v;
    }
}

extern "C" void kernel_launch(void* const* d_in, const int* in_sizes, int n_in,
                              void* d_out, int out_size, void* d_ws, size_t ws_size,
                              hipStream_t stream) {
    const float* x     = (const float*)d_in[0];
    const int*   ei    = (const int*)d_in[1];
    const float* W1    = (const float*)d_in[2];
    const float* as1   = (const float*)d_in[3];
    const float* ad1   = (const float*)d_in[4];
    const float* b1    = (const float*)d_in[5];
    const float* gamma = (const float*)d_in[6];
    const float* beta  = (const float*)d_in[7];
    const float* mean  = (const float*)d_in[8];
    const float* var   = (const float*)d_in[9];
    const float* W2    = (const float*)d_in[10];
    const float* as2   = (const float*)d_in[11];
    const float* ad2   = (const float*)d_in[12];
    const float* b2    = (const float*)d_in[13];
    const float* Wf    = (const float*)d_in[14];
    const float* bf    = (const float*)d_in[15];
    float* out = (float*)d_out;
    const int* esrc = ei;
    const int* edst = ei + E_EDGES;

    char* ws = (char*)d_ws;
    size_t off = 0;
    auto alloc = [&](size_t bytes) {
        char* p = ws + off;
        off += (bytes + 255) & ~(size_t)255;
        return p;
    };
    unsigned* Ghist = (unsigned*)alloc((size_t)NSCAN * 4);
    unsigned* Goff  = (unsigned*)alloc((size_t)NSCAN * 4);
    int* partbase   = (int*)alloc((size_t)(P_PART + 1) * 4);
    unsigned* Gpart = (unsigned*)alloc((size_t)E_TOT * 4);
    int* ptr              = (int*)alloc((size_t)(N_NODES + 1) * 4);
    unsigned* srec        = (unsigned*)alloc((size_t)E_TOT * 4);
    uint2* wrec           = (uint2*)alloc((size_t)E_TOT * 8);
    __hip_bfloat16* hbuf  = (__hip_bfloat16*)alloc((size_t)N_NODES * 64 * 2);
    float* x1buf = (float*)alloc((size_t)N_NODES * 64 * 4);
    float* asrc  = (float*)alloc((size_t)N_NODES * 2 * 4);
    float* adst  = (float*)alloc((size_t)N_NODES * 2 * 4);
    (void)ws_size; (void)in_sizes; (void)n_in; (void)out_size;

    const int NB = (N_NODES + 3) / 4;
    const int GT = (N_NODES + 63) / 64;   // GEMM tiles

    // ---------- CSR build (atomic-free partition sort, once) ----------
    hist_kernel<<<B1, 256, 0, stream>>>(edst, Ghist);
    scan2_kernel<<<1, 1024, 0, stream>>>(Ghist, Goff);
    partbase_kernel<<<1, 256, 0, stream>>>(Goff, partbase, ptr);
    scat2_kernel<<<B1, 256, 0, stream>>>(esrc, edst, Goff, Gpart);
    csr_kernel<<<P_PART, 256, 0, stream>>>(partbase, Gpart, ptr, srec);

    // ---------- layer 1 ----------
    lin_att_kernel<128><<<GT, 256, 0, stream>>>(x, W1, as1, ad1, hbuf, asrc, adst);
    ew_kernel<<<P_PART * 4, 256, 0, stream>>>(partbase, srec,
        (const float2*)asrc, (const float2*)adst, wrec);
    gat_agg_kernel<true, false><<<NB, 256, 0, stream>>>(ptr, wrec, hbuf,
        b1, gamma, beta, mean, var, x1buf, nullptr, nullptr, nullptr, nullptr);

    // ---------- layer 2 (+ fused JK + final linear + log_softmax) ----------
    lin_att_kernel<64><<<GT, 256, 0, stream>>>(x1buf, W2, as2, ad2, hbuf, asrc, adst);
    ew_kernel<<<P_PART * 4, 256, 0, stream>>>(partbase, srec,
        (const float2*)asrc, (const float2*)adst, wrec);
    gat_agg_kernel<false, true><<<NB, 256, 0, stream>>>(ptr, wrec, hbuf,
        b2, nullptr, nullptr, nullptr, nullptr, nullptr, x1buf, Wf, bf, out);
}

// Round 18
// 259.895 us; speedup vs baseline: 1.1178x; 1.0044x over previous
//
#include <hip/hip_runtime.h>
#include <hip/hip_bf16.h>
#include <math.h>

#define N_NODES 50000
#define E_EDGES 1200000
#define E_TOT   (E_EDGES + N_NODES)
#define NEG_SLOPE 0.2f
#define BN_EPS 1e-5f
#define P_PART 196          // partitions of 256 nodes (dst >> 8)
#define B1 64               // blocks in hist/scatter passes
#define NSCAN (P_PART * B1) // 12544

// wave-uniform lane broadcasts via v_readlane (SGPR path, no LDS/bpermute)
__device__ __forceinline__ int rl_i(int v, int l) {
    return __builtin_amdgcn_readlane(v, l);
}
__device__ __forceinline__ float rl_f(float v, int l) {
    return __uint_as_float(__builtin_amdgcn_readlane(__float_as_uint(v), l));
}
// fp32 -> bf16 bits with round-to-nearest-even
__device__ __forceinline__ unsigned bf16_bits(float f) {
    unsigned u = __float_as_uint(f);
    return (u + 0x7FFFu + ((u >> 16) & 1u)) >> 16;
}

// ==================== atomic-free CSR build (partition sort) =============
__global__ void hist_kernel(const int* __restrict__ edst, unsigned* __restrict__ Ghist) {
    __shared__ unsigned hist[P_PART];
    for (int i = threadIdx.x; i < P_PART; i += 256) hist[i] = 0;
    __syncthreads();
    const int chunk = (E_TOT + B1 - 1) / B1;
    const int beg = blockIdx.x * chunk;
    const int end = min(beg + chunk, E_TOT);
    for (int i = beg + threadIdx.x; i < end; i += 256) {
        int d = (i < E_EDGES) ? edst[i] : (i - E_EDGES);
        atomicAdd(&hist[d >> 8], 1u);          // LDS atomic
    }
    __syncthreads();
    for (int p = threadIdx.x; p < P_PART; p += 256)
        Ghist[p * B1 + blockIdx.x] = hist[p];  // bin-major for scan
}

__global__ void scan2_kernel(const unsigned* __restrict__ Ghist, unsigned* __restrict__ Goff) {
    __shared__ unsigned lds[1024];
    const int t = threadIdx.x;
    const int C = (NSCAN + 1023) / 1024;
    const int beg = t * C;
    const int end = min(beg + C, NSCAN);
    unsigned sum = 0;
    for (int i = beg; i < end; ++i) sum += Ghist[i];
    lds[t] = sum;
    __syncthreads();
    for (int off = 1; off < 1024; off <<= 1) {
        unsigned x = (t >= off) ? lds[t - off] : 0;
        __syncthreads();
        lds[t] += x;
        __syncthreads();
    }
    unsigned run = (t == 0) ? 0 : lds[t - 1];
    for (int i = beg; i < end; ++i) { Goff[i] = run; run += Ghist[i]; }
}

__global__ void partbase_kernel(const unsigned* __restrict__ Goff,
                                int* __restrict__ partbase, int* __restrict__ ptr) {
    int p = threadIdx.x;
    if (p < P_PART) partbase[p] = (int)Goff[p * B1];
    if (p == P_PART) partbase[P_PART] = E_TOT;
    if (p == 0) ptr[N_NODES] = E_TOT;
}

__global__ void scat2_kernel(const int* __restrict__ esrc, const int* __restrict__ edst,
                             const unsigned* __restrict__ Goff, unsigned* __restrict__ Gpart) {
    __shared__ unsigned cur[P_PART];
    for (int p = threadIdx.x; p < P_PART; p += 256) cur[p] = Goff[p * B1 + blockIdx.x];
    __syncthreads();
    const int chunk = (E_TOT + B1 - 1) / B1;
    const int beg = blockIdx.x * chunk;
    const int end = min(beg + chunk, E_TOT);
    for (int i = beg + threadIdx.x; i < end; i += 256) {
        int s = (i < E_EDGES) ? esrc[i] : (i - E_EDGES);
        int d = (i < E_EDGES) ? edst[i] : (i - E_EDGES);
        unsigned slot = atomicAdd(&cur[d >> 8], 1u);   // LDS atomic
        Gpart[slot] = ((unsigned)(d & 255) << 16) | (unsigned)s;
    }
}

// sorts within partition by node; emits srec u32 = (dlocal<<16 | src)
__global__ void csr_kernel(const int* __restrict__ partbase, const unsigned* __restrict__ Gpart,
                           int* __restrict__ ptr, unsigned* __restrict__ srec) {
    __shared__ unsigned deg[256];
    __shared__ unsigned scn[256];
    const int p = blockIdx.x;
    const int t = threadIdx.x;
    const int base = partbase[p];
    const int cnt = partbase[p + 1] - base;
    deg[t] = 0;
    __syncthreads();
    for (int i = t; i < cnt; i += 256)
        atomicAdd(&deg[Gpart[base + i] >> 16], 1u);
    __syncthreads();
    unsigned v = deg[t];
    scn[t] = v;
    __syncthreads();
    for (int o = 1; o < 256; o <<= 1) {
        unsigned x = (t >= o) ? scn[t - o] : 0;
        __syncthreads();
        scn[t] += x;
        __syncthreads();
    }
    unsigned excl = scn[t] - v;           // exclusive prefix
    int node = p * 256 + t;
    if (node < N_NODES) ptr[node] = base + (int)excl;
    __syncthreads();
    deg[t] = excl;                        // reuse deg[] as cursor
    __syncthreads();
    for (int i = t; i < cnt; i += 256) {
        unsigned rec = Gpart[base + i];
        unsigned slot = atomicAdd(&deg[rec >> 16], 1u);   // LDS atomic
        srec[base + slot] = rec;
    }
}

// ==================== per-layer edge-weight precompute ===================
// wrec = {src, w0bf16 | w1bf16<<16}
__global__ void ew_kernel(const int* __restrict__ partbase,
                          const unsigned* __restrict__ srec,
                          const float2* __restrict__ asrc,
                          const float2* __restrict__ adst,
                          uint2* __restrict__ wrec) {
    __shared__ float2 sad[256];
    const int p = blockIdx.x >> 2, q = blockIdx.x & 3;
    const int t = threadIdx.x;
    {
        int node = p * 256 + t;
        sad[t] = (node < N_NODES) ? adst[node] : make_float2(0.f, 0.f);
    }
    __syncthreads();
    const int base = partbase[p];
    const int cnt = partbase[p + 1] - base;
    const int qbeg = base + (cnt * q) / 4;
    const int qend = base + (cnt * (q + 1)) / 4;
    for (int i = qbeg + t; i < qend; i += 256) {
        unsigned rec = srec[i];
        int s  = (int)(rec & 0xFFFFu);
        int dl = (int)(rec >> 16);
        float2 a = asrc[s];
        float2 b = sad[dl];
        float e0 = a.x + b.x; e0 = e0 > 0.f ? e0 : NEG_SLOPE * e0;
        float e1 = a.y + b.y; e1 = e1 > 0.f ? e1 : NEG_SLOPE * e1;
        wrec[i] = make_uint2((unsigned)s,
                             bf16_bits(__expf(e0)) | (bf16_bits(__expf(e1)) << 16));
    }
}

// ==================== h = x @ W : register-tiled GEMM ====================
template<int K>
__global__ __launch_bounds__(256) void lin_att_kernel(
        const float* __restrict__ x, const float* __restrict__ W,
        const float* __restrict__ a_s, const float* __restrict__ a_d,
        __hip_bfloat16* __restrict__ h, float* __restrict__ asrc,
        float* __restrict__ adst) {
    __shared__ float sx[64 * (K + 1)];
    __shared__ float sW[K * 64];
    const int tid = threadIdx.x;
    for (int i = tid; i < K * 64; i += 256) sW[i] = W[i];
    const int ng = tid >> 4;          // node group 0..15 -> nodes ng*4..+3
    const int cg = tid & 15;          // channel group -> channels cg*4..+3
    const int c0 = cg * 4;
    const float4 asv = *(const float4*)&a_s[c0];
    const float4 adv = *(const float4*)&a_d[c0];
    const int ntiles = (N_NODES + 63) / 64;
    for (int tile = blockIdx.x; tile < ntiles; tile += gridDim.x) {
        const int nbase = tile * 64;
        __syncthreads();
        for (int i = tid; i < 64 * K; i += 256) {
            int n = i / K, k = i - n * K;
            int node = nbase + n;
            sx[n * (K + 1) + k] = (node < N_NODES) ? x[(size_t)node * K + k] : 0.f;
        }
        __syncthreads();
        float acc[4][4] = {};
        #pragma unroll 4
        for (int k = 0; k < K; ++k) {
            float4 wv = *(const float4*)&sW[k * 64 + c0];
            #pragma unroll
            for (int j = 0; j < 4; ++j) {
                float xv = sx[(ng * 4 + j) * (K + 1) + k];
                acc[j][0] = fmaf(xv, wv.x, acc[j][0]);
                acc[j][1] = fmaf(xv, wv.y, acc[j][1]);
                acc[j][2] = fmaf(xv, wv.z, acc[j][2]);
                acc[j][3] = fmaf(xv, wv.w, acc[j][3]);
            }
        }
        #pragma unroll
        for (int j = 0; j < 4; ++j) {
            int node = nbase + ng * 4 + j;
            float ps = acc[j][0] * asv.x + acc[j][1] * asv.y +
                       acc[j][2] * asv.z + acc[j][3] * asv.w;
            float pd = acc[j][0] * adv.x + acc[j][1] * adv.y +
                       acc[j][2] * adv.z + acc[j][3] * adv.w;
            #pragma unroll
            for (int o = 1; o < 8; o <<= 1) {
                ps += __shfl_xor(ps, o, 64);
                pd += __shfl_xor(pd, o, 64);
            }
            if (node < N_NODES) {
                ushort4 pk;
                pk.x = (unsigned short)bf16_bits(acc[j][0]);
                pk.y = (unsigned short)bf16_bits(acc[j][1]);
                pk.z = (unsigned short)bf16_bits(acc[j][2]);
                pk.w = (unsigned short)bf16_bits(acc[j][3]);
                *(ushort4*)&h[(size_t)node * 64 + c0] = pk;
                if ((cg & 7) == 0) {
                    int head = cg >> 3;
                    asrc[node * 2 + head] = ps;
                    adst[node * 2 + head] = pd;
                }
            }
        }
    }
}

// ==================== fused GAT aggregate: 4 edges / wave-step ===========
// lane = slot*16 + cg: slot owns edge (group*4+slot), cg owns channels
// cg*4..+3. Per group: 16 lanes share one 8B wrec read (HW broadcast),
// each lane 1x ushort4 h read (wave = 4 full rows, coalesced), 4 FMA.
// Denominator s falls out per-lane; slot-reduce (xor 16,32) once per node.
template<bool BN, bool FINAL>
__global__ void gat_agg_kernel(const int* __restrict__ ptr,
                               const uint2* __restrict__ wrec,
                               const __hip_bfloat16* __restrict__ h,
                               const float* __restrict__ bias,
                               const float* __restrict__ gamma, const float* __restrict__ beta,
                               const float* __restrict__ mean, const float* __restrict__ var,
                               float* __restrict__ out,
                               const float* __restrict__ x1, const float* __restrict__ Wf,
                               const float* __restrict__ bf, float* __restrict__ out40) {
    __shared__ float sWf[FINAL ? 64 * 40 : 1];
    if constexpr (FINAL) {
        for (int i = threadIdx.x; i < 64 * 40; i += 256) sWf[i] = Wf[i];
        __syncthreads();
    }
    int node = blockIdx.x * 4 + (threadIdx.x >> 6);
    if (node >= N_NODES) return;
    const int lane = threadIdx.x & 63;
    const int slot = lane >> 4;        // 0..3: edge slot
    const int cg   = lane & 15;        // channel group: channels cg*4..+3
    const int c0 = cg * 4;
    const unsigned shl = (cg < 8) ? 16u : 0u;   // head0 = low half of rec.y
    const unsigned coff = (unsigned)(cg * 8);
    const char* hb = (const char*)h;
    float a0 = 0.f, a1 = 0.f, a2 = 0.f, a3 = 0.f, s = 0.f;
    const int beg = ptr[node], end = ptr[node + 1];
    const int deg = end - beg;
    const uint2* rp = wrec + beg + slot;
    const int nfull = deg >> 2;

#define GRP(R) {                                                             \
        float wv = __uint_as_float(((R).y << shl) & 0xFFFF0000u);            \
        uint2 hh = *(const uint2*)(hb + (((R).x << 7) + coff));              \
        a0 = fmaf(wv, __uint_as_float(hh.x << 16), a0);                      \
        a1 = fmaf(wv, __uint_as_float(hh.x & 0xFFFF0000u), a1);              \
        a2 = fmaf(wv, __uint_as_float(hh.y << 16), a2);                      \
        a3 = fmaf(wv, __uint_as_float(hh.y & 0xFFFF0000u), a3);              \
        s += wv; }

    int g = 0;
    for (; g + 2 <= nfull; g += 2) {
        uint2 r0 = rp[g * 4];
        uint2 r1 = rp[g * 4 + 4];
        GRP(r0) GRP(r1)
    }
    if (g < nfull) { uint2 r0 = rp[g * 4]; GRP(r0) }
    const int rem = deg & 3;
    if (rem) {
        uint2 r0 = rp[nfull * 4];      // padded read (wrec has +64 pad)
        if (slot >= rem) r0 = make_uint2(0u, 0u);  // mask BOTH src and w
        GRP(r0)
    }
#undef GRP

    // reduce over slots (xor 16,32 preserve cg)
    #pragma unroll
    for (int o = 16; o < 64; o <<= 1) {
        a0 += __shfl_xor(a0, o, 64);
        a1 += __shfl_xor(a1, o, 64);
        a2 += __shfl_xor(a2, o, 64);
        a3 += __shfl_xor(a3, o, 64);
        s  += __shfl_xor(s, o, 64);
    }
    const float inv = 1.f / (s + 1e-16f);
    float4 bv = *(const float4*)&bias[c0];
    float v0 = a0 * inv + bv.x;
    float v1 = a1 * inv + bv.y;
    float v2 = a2 * inv + bv.z;
    float v3 = a3 * inv + bv.w;
    if constexpr (BN) {
        float4 mn = *(const float4*)&mean[c0];
        float4 vr = *(const float4*)&var[c0];
        float4 gm = *(const float4*)&gamma[c0];
        float4 bt = *(const float4*)&beta[c0];
        v0 = (v0 - mn.x) * rsqrtf(vr.x + BN_EPS) * gm.x + bt.x;
        v1 = (v1 - mn.y) * rsqrtf(vr.y + BN_EPS) * gm.y + bt.y;
        v2 = (v2 - mn.z) * rsqrtf(vr.z + BN_EPS) * gm.z + bt.z;
        v3 = (v3 - mn.w) * rsqrtf(vr.w + BN_EPS) * gm.w + bt.w;
        v0 = v0 > 0.f ? v0 : (__expf(v0) - 1.f);
        v1 = v1 > 0.f ? v1 : (__expf(v1) - 1.f);
        v2 = v2 > 0.f ? v2 : (__expf(v2) - 1.f);
        v3 = v3 > 0.f ? v3 : (__expf(v3) - 1.f);
    }
    if constexpr (FINAL) {
        float4 x1v = *(const float4*)&x1[(size_t)node * 64 + c0];
        float jk0 = fmaxf(x1v.x, v0);
        float jk1 = fmaxf(x1v.y, v1);
        float jk2 = fmaxf(x1v.z, v2);
        float jk3 = fmaxf(x1v.w, v3);
        const int o = (lane < 40) ? lane : 0;
        float dot = 0.f;
        #pragma unroll
        for (int c = 0; c < 64; c += 4) {
            // jk for channel c lives (duplicated) in lane c>>2 (slot 0)
            dot = fmaf(rl_f(jk0, c >> 2), sWf[(c + 0) * 40 + o], dot);
            dot = fmaf(rl_f(jk1, c >> 2), sWf[(c + 1) * 40 + o], dot);
            dot = fmaf(rl_f(jk2, c >> 2), sWf[(c + 2) * 40 + o], dot);
            dot = fmaf(rl_f(jk3, c >> 2), sWf[(c + 3) * 40 + o], dot);
        }
        float logit = (lane < 40) ? (dot + bf[o]) : -INFINITY;
        float mx = logit;
        #pragma unroll
        for (int mm = 1; mm < 64; mm <<= 1) mx = fmaxf(mx, __shfl_xor(mx, mm, 64));
        float ex = (lane < 40) ? __expf(logit - mx) : 0.f;
        float sum = ex;
        #pragma unroll
        for (int mm = 1; mm < 64; mm <<= 1) sum += __shfl_xor(sum, mm, 64);
        if (lane < 40) out40[node * 40 + lane] = logit - mx - logf(sum);
    } else {
        if (slot == 0) {
            float4 v4 = make_float4(v0, v1, v2, v3);
            *(float4*)&out[(size_t)node * 64 + c0] = v4;
        }
    }
}

extern "C" void kernel_launch(void* const* d_in, const int* in_sizes, int n_in,
                              void* d_out, int out_size, void* d_ws, size_t ws_size,
                              hipStream_t stream) {
    const float* x     = (const float*)d_in[0];
    const int*   ei    = (const int*)d_in[1];
    const float* W1    = (const float*)d_in[2];
    const float* as1   = (const float*)d_in[3];
    const float* ad1   = (const float*)d_in[4];
    const float* b1    = (const float*)d_in[5];
    const float* gamma = (const float*)d_in[6];
    const float* beta  = (const float*)d_in[7];
    const float* mean  = (const float*)d_in[8];
    const float* var   = (const float*)d_in[9];
    const float* W2    = (const float*)d_in[10];
    const float* as2   = (const float*)d_in[11];
    const float* ad2   = (const float*)d_in[12];
    const float* b2    = (const float*)d_in[13];
    const float* Wf    = (const float*)d_in[14];
    const float* bf    = (const float*)d_in[15];
    float* out = (float*)d_out;
    const int* esrc = ei;
    const int* edst = ei + E_EDGES;

    char* ws = (char*)d_ws;
    size_t off = 0;
    auto alloc = [&](size_t bytes) {
        char* p = ws + off;
        off += (bytes + 255) & ~(size_t)255;
        return p;
    };
    unsigned* Ghist = (unsigned*)alloc((size_t)NSCAN * 4);
    unsigned* Goff  = (unsigned*)alloc((size_t)NSCAN * 4);
    int* partbase   = (int*)alloc((size_t)(P_PART + 1) * 4);
    unsigned* Gpart = (unsigned*)alloc((size_t)E_TOT * 4);
    int* ptr              = (int*)alloc((size_t)(N_NODES + 1) * 4);
    unsigned* srec        = (unsigned*)alloc((size_t)E_TOT * 4);
    uint2* wrec           = (uint2*)alloc(((size_t)E_TOT + 64) * 8);  // +pad for tail reads
    __hip_bfloat16* hbuf  = (__hip_bfloat16*)alloc((size_t)N_NODES * 64 * 2);
    float* x1buf = (float*)alloc((size_t)N_NODES * 64 * 4);
    float* asrc  = (float*)alloc((size_t)N_NODES * 2 * 4);
    float* adst  = (float*)alloc((size_t)N_NODES * 2 * 4);
    (void)ws_size; (void)in_sizes; (void)n_in; (void)out_size;

    const int NB = (N_NODES + 3) / 4;
    const int GT = (N_NODES + 63) / 64;   // GEMM tiles

    // ---------- CSR build (atomic-free partition sort, once) ----------
    hist_kernel<<<B1, 256, 0, stream>>>(edst, Ghist);
    scan2_kernel<<<1, 1024, 0, stream>>>(Ghist, Goff);
    partbase_kernel<<<1, 256, 0, stream>>>(Goff, partbase, ptr);
    scat2_kernel<<<B1, 256, 0, stream>>>(esrc, edst, Goff, Gpart);
    csr_kernel<<<P_PART, 256, 0, stream>>>(partbase, Gpart, ptr, srec);

    // ---------- layer 1 ----------
    lin_att_kernel<128><<<GT, 256, 0, stream>>>(x, W1, as1, ad1, hbuf, asrc, adst);
    ew_kernel<<<P_PART * 4, 256, 0, stream>>>(partbase, srec,
        (const float2*)asrc, (const float2*)adst, wrec);
    gat_agg_kernel<true, false><<<NB, 256, 0, stream>>>(ptr, wrec, hbuf,
        b1, gamma, beta, mean, var, x1buf, nullptr, nullptr, nullptr, nullptr);

    // ---------- layer 2 (+ fused JK + final linear + log_softmax) ----------
    lin_att_kernel<64><<<GT, 256, 0, stream>>>(x1buf, W2, as2, ad2, hbuf, asrc, adst);
    ew_kernel<<<P_PART * 4, 256, 0, stream>>>(partbase, srec,
        (const float2*)asrc, (const float2*)adst, wrec);
    gat_agg_kernel<false, true><<<NB, 256, 0, stream>>>(ptr, wrec, hbuf,
        b2, nullptr, nullptr, nullptr, nullptr, nullptr, x1buf, Wf, bf, out);
}

// Round 19
// 258.287 us; speedup vs baseline: 1.1248x; 1.0062x over previous
//
#include <hip/hip_runtime.h>
#include <hip/hip_bf16.h>
#include <math.h>

#define N_NODES 50000
#define E_EDGES 1200000
#define E_TOT   (E_EDGES + N_NODES)
#define NEG_SLOPE 0.2f
#define BN_EPS 1e-5f
#define P_PART 196          // partitions of 256 nodes (dst >> 8)
#define B1 64               // blocks in hist/scatter passes
#define NSCAN (P_PART * B1) // 12544

// wave-uniform lane broadcasts via v_readlane (SGPR path, no LDS/bpermute)
__device__ __forceinline__ int rl_i(int v, int l) {
    return __builtin_amdgcn_readlane(v, l);
}
__device__ __forceinline__ float rl_f(float v, int l) {
    return __uint_as_float(__builtin_amdgcn_readlane(__float_as_uint(v), l));
}
// fp32 -> bf16 bits with round-to-nearest-even
__device__ __forceinline__ unsigned bf16_bits(float f) {
    unsigned u = __float_as_uint(f);
    return (u + 0x7FFFu + ((u >> 16) & 1u)) >> 16;
}

// ==================== atomic-free CSR build (partition sort) =============
__global__ void hist_kernel(const int* __restrict__ edst, unsigned* __restrict__ Ghist) {
    __shared__ unsigned hist[P_PART];
    for (int i = threadIdx.x; i < P_PART; i += 256) hist[i] = 0;
    __syncthreads();
    const int chunk = (E_TOT + B1 - 1) / B1;
    const int beg = blockIdx.x * chunk;
    const int end = min(beg + chunk, E_TOT);
    for (int i = beg + threadIdx.x; i < end; i += 256) {
        int d = (i < E_EDGES) ? edst[i] : (i - E_EDGES);
        atomicAdd(&hist[d >> 8], 1u);          // LDS atomic
    }
    __syncthreads();
    for (int p = threadIdx.x; p < P_PART; p += 256)
        Ghist[p * B1 + blockIdx.x] = hist[p];  // bin-major for scan
}

__global__ void scan2_kernel(const unsigned* __restrict__ Ghist, unsigned* __restrict__ Goff) {
    __shared__ unsigned lds[1024];
    const int t = threadIdx.x;
    const int C = (NSCAN + 1023) / 1024;
    const int beg = t * C;
    const int end = min(beg + C, NSCAN);
    unsigned sum = 0;
    for (int i = beg; i < end; ++i) sum += Ghist[i];
    lds[t] = sum;
    __syncthreads();
    for (int off = 1; off < 1024; off <<= 1) {
        unsigned x = (t >= off) ? lds[t - off] : 0;
        __syncthreads();
        lds[t] += x;
        __syncthreads();
    }
    unsigned run = (t == 0) ? 0 : lds[t - 1];
    for (int i = beg; i < end; ++i) { Goff[i] = run; run += Ghist[i]; }
}

__global__ void partbase_kernel(const unsigned* __restrict__ Goff,
                                int* __restrict__ partbase, int* __restrict__ ptr) {
    int p = threadIdx.x;
    if (p < P_PART) partbase[p] = (int)Goff[p * B1];
    if (p == P_PART) partbase[P_PART] = E_TOT;
    if (p == 0) ptr[N_NODES] = E_TOT;
}

__global__ void scat2_kernel(const int* __restrict__ esrc, const int* __restrict__ edst,
                             const unsigned* __restrict__ Goff, unsigned* __restrict__ Gpart) {
    __shared__ unsigned cur[P_PART];
    for (int p = threadIdx.x; p < P_PART; p += 256) cur[p] = Goff[p * B1 + blockIdx.x];
    __syncthreads();
    const int chunk = (E_TOT + B1 - 1) / B1;
    const int beg = blockIdx.x * chunk;
    const int end = min(beg + chunk, E_TOT);
    for (int i = beg + threadIdx.x; i < end; i += 256) {
        int s = (i < E_EDGES) ? esrc[i] : (i - E_EDGES);
        int d = (i < E_EDGES) ? edst[i] : (i - E_EDGES);
        unsigned slot = atomicAdd(&cur[d >> 8], 1u);   // LDS atomic
        Gpart[slot] = ((unsigned)(d & 255) << 16) | (unsigned)s;
    }
}

// sorts within partition by node; emits srec u32 = (dlocal<<16 | src)
__global__ void csr_kernel(const int* __restrict__ partbase, const unsigned* __restrict__ Gpart,
                           int* __restrict__ ptr, unsigned* __restrict__ srec) {
    __shared__ unsigned deg[256];
    __shared__ unsigned scn[256];
    const int p = blockIdx.x;
    const int t = threadIdx.x;
    const int base = partbase[p];
    const int cnt = partbase[p + 1] - base;
    deg[t] = 0;
    __syncthreads();
    for (int i = t; i < cnt; i += 256)
        atomicAdd(&deg[Gpart[base + i] >> 16], 1u);
    __syncthreads();
    unsigned v = deg[t];
    scn[t] = v;
    __syncthreads();
    for (int o = 1; o < 256; o <<= 1) {
        unsigned x = (t >= o) ? scn[t - o] : 0;
        __syncthreads();
        scn[t] += x;
        __syncthreads();
    }
    unsigned excl = scn[t] - v;           // exclusive prefix
    int node = p * 256 + t;
    if (node < N_NODES) ptr[node] = base + (int)excl;
    __syncthreads();
    deg[t] = excl;                        // reuse deg[] as cursor
    __syncthreads();
    for (int i = t; i < cnt; i += 256) {
        unsigned rec = Gpart[base + i];
        unsigned slot = atomicAdd(&deg[rec >> 16], 1u);   // LDS atomic
        srec[base + slot] = rec;
    }
}

// ==================== per-layer edge-weight precompute ===================
// wrec = {src, w0bf16 | w1bf16<<16}
__global__ void ew_kernel(const int* __restrict__ partbase,
                          const unsigned* __restrict__ srec,
                          const float2* __restrict__ asrc,
                          const float2* __restrict__ adst,
                          uint2* __restrict__ wrec) {
    __shared__ float2 sad[256];
    const int p = blockIdx.x >> 2, q = blockIdx.x & 3;
    const int t = threadIdx.x;
    {
        int node = p * 256 + t;
        sad[t] = (node < N_NODES) ? adst[node] : make_float2(0.f, 0.f);
    }
    __syncthreads();
    const int base = partbase[p];
    const int cnt = partbase[p + 1] - base;
    const int qbeg = base + (cnt * q) / 4;
    const int qend = base + (cnt * (q + 1)) / 4;
    for (int i = qbeg + t; i < qend; i += 256) {
        unsigned rec = srec[i];
        int s  = (int)(rec & 0xFFFFu);
        int dl = (int)(rec >> 16);
        float2 a = asrc[s];
        float2 b = sad[dl];
        float e0 = a.x + b.x; e0 = e0 > 0.f ? e0 : NEG_SLOPE * e0;
        float e1 = a.y + b.y; e1 = e1 > 0.f ? e1 : NEG_SLOPE * e1;
        wrec[i] = make_uint2((unsigned)s,
                             bf16_bits(__expf(e0)) | (bf16_bits(__expf(e1)) << 16));
    }
}

// ==================== h = x @ W : register-tiled GEMM ====================
template<int K>
__global__ __launch_bounds__(256) void lin_att_kernel(
        const float* __restrict__ x, const float* __restrict__ W,
        const float* __restrict__ a_s, const float* __restrict__ a_d,
        __hip_bfloat16* __restrict__ h, float* __restrict__ asrc,
        float* __restrict__ adst) {
    __shared__ float sx[64 * (K + 1)];
    __shared__ float sW[K * 64];
    const int tid = threadIdx.x;
    for (int i = tid; i < K * 64; i += 256) sW[i] = W[i];
    const int ng = tid >> 4;          // node group 0..15 -> nodes ng*4..+3
    const int cg = tid & 15;          // channel group -> channels cg*4..+3
    const int c0 = cg * 4;
    const float4 asv = *(const float4*)&a_s[c0];
    const float4 adv = *(const float4*)&a_d[c0];
    const int ntiles = (N_NODES + 63) / 64;
    for (int tile = blockIdx.x; tile < ntiles; tile += gridDim.x) {
        const int nbase = tile * 64;
        __syncthreads();
        for (int i = tid; i < 64 * K; i += 256) {
            int n = i / K, k = i - n * K;
            int node = nbase + n;
            sx[n * (K + 1) + k] = (node < N_NODES) ? x[(size_t)node * K + k] : 0.f;
        }
        __syncthreads();
        float acc[4][4] = {};
        #pragma unroll 4
        for (int k = 0; k < K; ++k) {
            float4 wv = *(const float4*)&sW[k * 64 + c0];
            #pragma unroll
            for (int j = 0; j < 4; ++j) {
                float xv = sx[(ng * 4 + j) * (K + 1) + k];
                acc[j][0] = fmaf(xv, wv.x, acc[j][0]);
                acc[j][1] = fmaf(xv, wv.y, acc[j][1]);
                acc[j][2] = fmaf(xv, wv.z, acc[j][2]);
                acc[j][3] = fmaf(xv, wv.w, acc[j][3]);
            }
        }
        #pragma unroll
        for (int j = 0; j < 4; ++j) {
            int node = nbase + ng * 4 + j;
            float ps = acc[j][0] * asv.x + acc[j][1] * asv.y +
                       acc[j][2] * asv.z + acc[j][3] * asv.w;
            float pd = acc[j][0] * adv.x + acc[j][1] * adv.y +
                       acc[j][2] * adv.z + acc[j][3] * adv.w;
            #pragma unroll
            for (int o = 1; o < 8; o <<= 1) {
                ps += __shfl_xor(ps, o, 64);
                pd += __shfl_xor(pd, o, 64);
            }
            if (node < N_NODES) {
                ushort4 pk;
                pk.x = (unsigned short)bf16_bits(acc[j][0]);
                pk.y = (unsigned short)bf16_bits(acc[j][1]);
                pk.z = (unsigned short)bf16_bits(acc[j][2]);
                pk.w = (unsigned short)bf16_bits(acc[j][3]);
                *(ushort4*)&h[(size_t)node * 64 + c0] = pk;
                if ((cg & 7) == 0) {
                    int head = cg >> 3;
                    asrc[node * 2 + head] = ps;
                    adst[node * 2 + head] = pd;
                }
            }
        }
    }
}

// ==================== fused GAT aggregate: 4 edges / wave-step ===========
// lane = slot*16 + cg. 4-deep group unroll: 4 wrec loads, then 4 h-row
// loads (8 outstanding VMEM/wave), then 20 FMAs -- latency-hiding MLP.
template<bool BN, bool FINAL>
__global__ void gat_agg_kernel(const int* __restrict__ ptr,
                               const uint2* __restrict__ wrec,
                               const __hip_bfloat16* __restrict__ h,
                               const float* __restrict__ bias,
                               const float* __restrict__ gamma, const float* __restrict__ beta,
                               const float* __restrict__ mean, const float* __restrict__ var,
                               float* __restrict__ out,
                               const float* __restrict__ x1, const float* __restrict__ Wf,
                               const float* __restrict__ bf, float* __restrict__ out40) {
    __shared__ float sWf[FINAL ? 64 * 40 : 1];
    if constexpr (FINAL) {
        for (int i = threadIdx.x; i < 64 * 40; i += 256) sWf[i] = Wf[i];
        __syncthreads();
    }
    int node = blockIdx.x * 4 + (threadIdx.x >> 6);
    if (node >= N_NODES) return;
    const int lane = threadIdx.x & 63;
    const int slot = lane >> 4;        // 0..3: edge slot
    const int cg   = lane & 15;        // channel group: channels cg*4..+3
    const int c0 = cg * 4;
    const unsigned shl = (cg < 8) ? 16u : 0u;   // head0 = low half of rec.y
    const unsigned coff = (unsigned)(cg * 8);
    const char* hb = (const char*)h;
    float a0 = 0.f, a1 = 0.f, a2 = 0.f, a3 = 0.f, s = 0.f;
    const int beg = ptr[node], end = ptr[node + 1];
    const int deg = end - beg;
    const uint2* rp = wrec + beg + slot;
    const int nfull = deg >> 2;

#define FMA4(WV, HH) {                                                       \
        a0 = fmaf(WV, __uint_as_float((HH).x << 16), a0);                    \
        a1 = fmaf(WV, __uint_as_float((HH).x & 0xFFFF0000u), a1);            \
        a2 = fmaf(WV, __uint_as_float((HH).y << 16), a2);                    \
        a3 = fmaf(WV, __uint_as_float((HH).y & 0xFFFF0000u), a3);            \
        s += WV; }
#define GRP(R) {                                                             \
        float wv = __uint_as_float(((R).y << shl) & 0xFFFF0000u);            \
        uint2 hh = *(const uint2*)(hb + (((R).x << 7) + coff));              \
        FMA4(wv, hh) }

    int g = 0;
    for (; g + 4 <= nfull; g += 4) {
        // cluster the 4 independent wrec loads
        uint2 r0 = rp[(g + 0) * 4];
        uint2 r1 = rp[(g + 1) * 4];
        uint2 r2 = rp[(g + 2) * 4];
        uint2 r3 = rp[(g + 3) * 4];
        // cluster the 4 independent h-row loads
        uint2 h0 = *(const uint2*)(hb + (((size_t)r0.x << 7) + coff));
        uint2 h1 = *(const uint2*)(hb + (((size_t)r1.x << 7) + coff));
        uint2 h2 = *(const uint2*)(hb + (((size_t)r2.x << 7) + coff));
        uint2 h3 = *(const uint2*)(hb + (((size_t)r3.x << 7) + coff));
        float w0 = __uint_as_float((r0.y << shl) & 0xFFFF0000u);
        float w1 = __uint_as_float((r1.y << shl) & 0xFFFF0000u);
        float w2 = __uint_as_float((r2.y << shl) & 0xFFFF0000u);
        float w3 = __uint_as_float((r3.y << shl) & 0xFFFF0000u);
        FMA4(w0, h0) FMA4(w1, h1) FMA4(w2, h2) FMA4(w3, h3)
    }
    for (; g < nfull; ++g) { uint2 r = rp[g * 4]; GRP(r) }
    const int rem = deg & 3;
    if (rem) {
        uint2 r0 = rp[nfull * 4];      // padded read (wrec has +64 pad)
        if (slot >= rem) r0 = make_uint2(0u, 0u);  // mask BOTH src and w
        GRP(r0)
    }
#undef GRP
#undef FMA4

    // reduce over slots (xor 16,32 preserve cg)
    #pragma unroll
    for (int o = 16; o < 64; o <<= 1) {
        a0 += __shfl_xor(a0, o, 64);
        a1 += __shfl_xor(a1, o, 64);
        a2 += __shfl_xor(a2, o, 64);
        a3 += __shfl_xor(a3, o, 64);
        s  += __shfl_xor(s, o, 64);
    }
    const float inv = 1.f / (s + 1e-16f);
    float4 bv = *(const float4*)&bias[c0];
    float v0 = a0 * inv + bv.x;
    float v1 = a1 * inv + bv.y;
    float v2 = a2 * inv + bv.z;
    float v3 = a3 * inv + bv.w;
    if constexpr (BN) {
        float4 mn = *(const float4*)&mean[c0];
        float4 vr = *(const float4*)&var[c0];
        float4 gm = *(const float4*)&gamma[c0];
        float4 bt = *(const float4*)&beta[c0];
        v0 = (v0 - mn.x) * rsqrtf(vr.x + BN_EPS) * gm.x + bt.x;
        v1 = (v1 - mn.y) * rsqrtf(vr.y + BN_EPS) * gm.y + bt.y;
        v2 = (v2 - mn.z) * rsqrtf(vr.z + BN_EPS) * gm.z + bt.z;
        v3 = (v3 - mn.w) * rsqrtf(vr.w + BN_EPS) * gm.w + bt.w;
        v0 = v0 > 0.f ? v0 : (__expf(v0) - 1.f);
        v1 = v1 > 0.f ? v1 : (__expf(v1) - 1.f);
        v2 = v2 > 0.f ? v2 : (__expf(v2) - 1.f);
        v3 = v3 > 0.f ? v3 : (__expf(v3) - 1.f);
    }
    if constexpr (FINAL) {
        float4 x1v = *(const float4*)&x1[(size_t)node * 64 + c0];
        float jk0 = fmaxf(x1v.x, v0);
        float jk1 = fmaxf(x1v.y, v1);
        float jk2 = fmaxf(x1v.z, v2);
        float jk3 = fmaxf(x1v.w, v3);
        const int o = (lane < 40) ? lane : 0;
        float dot = 0.f;
        #pragma unroll
        for (int c = 0; c < 64; c += 4) {
            // jk for channel c lives (duplicated) in lane c>>2 (slot 0)
            dot = fmaf(rl_f(jk0, c >> 2), sWf[(c + 0) * 40 + o], dot);
            dot = fmaf(rl_f(jk1, c >> 2), sWf[(c + 1) * 40 + o], dot);
            dot = fmaf(rl_f(jk2, c >> 2), sWf[(c + 2) * 40 + o], dot);
            dot = fmaf(rl_f(jk3, c >> 2), sWf[(c + 3) * 40 + o], dot);
        }
        float logit = (lane < 40) ? (dot + bf[o]) : -INFINITY;
        float mx = logit;
        #pragma unroll
        for (int mm = 1; mm < 64; mm <<= 1) mx = fmaxf(mx, __shfl_xor(mx, mm, 64));
        float ex = (lane < 40) ? __expf(logit - mx) : 0.f;
        float sum = ex;
        #pragma unroll
        for (int mm = 1; mm < 64; mm <<= 1) sum += __shfl_xor(sum, mm, 64);
        if (lane < 40) out40[node * 40 + lane] = logit - mx - logf(sum);
    } else {
        if (slot == 0) {
            float4 v4 = make_float4(v0, v1, v2, v3);
            *(float4*)&out[(size_t)node * 64 + c0] = v4;
        }
    }
}

extern "C" void kernel_launch(void* const* d_in, const int* in_sizes, int n_in,
                              void* d_out, int out_size, void* d_ws, size_t ws_size,
                              hipStream_t stream) {
    const float* x     = (const float*)d_in[0];
    const int*   ei    = (const int*)d_in[1];
    const float* W1    = (const float*)d_in[2];
    const float* as1   = (const float*)d_in[3];
    const float* ad1   = (const float*)d_in[4];
    const float* b1    = (const float*)d_in[5];
    const float* gamma = (const float*)d_in[6];
    const float* beta  = (const float*)d_in[7];
    const float* mean  = (const float*)d_in[8];
    const float* var   = (const float*)d_in[9];
    const float* W2    = (const float*)d_in[10];
    const float* as2   = (const float*)d_in[11];
    const float* ad2   = (const float*)d_in[12];
    const float* b2    = (const float*)d_in[13];
    const float* Wf    = (const float*)d_in[14];
    const float* bf    = (const float*)d_in[15];
    float* out = (float*)d_out;
    const int* esrc = ei;
    const int* edst = ei + E_EDGES;

    char* ws = (char*)d_ws;
    size_t off = 0;
    auto alloc = [&](size_t bytes) {
        char* p = ws + off;
        off += (bytes + 255) & ~(size_t)255;
        return p;
    };
    unsigned* Ghist = (unsigned*)alloc((size_t)NSCAN * 4);
    unsigned* Goff  = (unsigned*)alloc((size_t)NSCAN * 4);
    int* partbase   = (int*)alloc((size_t)(P_PART + 1) * 4);
    unsigned* Gpart = (unsigned*)alloc((size_t)E_TOT * 4);
    int* ptr              = (int*)alloc((size_t)(N_NODES + 1) * 4);
    unsigned* srec        = (unsigned*)alloc((size_t)E_TOT * 4);
    uint2* wrec           = (uint2*)alloc(((size_t)E_TOT + 64) * 8);  // +pad for tail reads
    __hip_bfloat16* hbuf  = (__hip_bfloat16*)alloc((size_t)N_NODES * 64 * 2);
    float* x1buf = (float*)alloc((size_t)N_NODES * 64 * 4);
    float* asrc  = (float*)alloc((size_t)N_NODES * 2 * 4);
    float* adst  = (float*)alloc((size_t)N_NODES * 2 * 4);
    (void)ws_size; (void)in_sizes; (void)n_in; (void)out_size;

    const int NB = (N_NODES + 3) / 4;
    const int GT = (N_NODES + 63) / 64;   // GEMM tiles

    // ---------- CSR build (atomic-free partition sort, once) ----------
    hist_kernel<<<B1, 256, 0, stream>>>(edst, Ghist);
    scan2_kernel<<<1, 1024, 0, stream>>>(Ghist, Goff);
    partbase_kernel<<<1, 256, 0, stream>>>(Goff, partbase, ptr);
    scat2_kernel<<<B1, 256, 0, stream>>>(esrc, edst, Goff, Gpart);
    csr_kernel<<<P_PART, 256, 0, stream>>>(partbase, Gpart, ptr, srec);

    // ---------- layer 1 ----------
    lin_att_kernel<128><<<GT, 256, 0, stream>>>(x, W1, as1, ad1, hbuf, asrc, adst);
    ew_kernel<<<P_PART * 4, 256, 0, stream>>>(partbase, srec,
        (const float2*)asrc, (const float2*)adst, wrec);
    gat_agg_kernel<true, false><<<NB, 256, 0, stream>>>(ptr, wrec, hbuf,
        b1, gamma, beta, mean, var, x1buf, nullptr, nullptr, nullptr, nullptr);

    // ---------- layer 2 (+ fused JK + final linear + log_softmax) ----------
    lin_att_kernel<64><<<GT, 256, 0, stream>>>(x1buf, W2, as2, ad2, hbuf, asrc, adst);
    ew_kernel<<<P_PART * 4, 256, 0, stream>>>(partbase, srec,
        (const float2*)asrc, (const float2*)adst, wrec);
    gat_agg_kernel<false, true><<<NB, 256, 0, stream>>>(ptr, wrec, hbuf,
        b2, nullptr, nullptr, nullptr, nullptr, nullptr, x1buf, Wf, bf, out);
}